// Round 2
// baseline (1116.318 us; speedup 1.0000x reference)
//
#include <hip/hip_runtime.h>
#include <hip/hip_fp16.h>
#include <stdint.h>
#include <stddef.h>

typedef float f32x4 __attribute__((ext_vector_type(4)));

#define GLOBAL_AS __attribute__((address_space(1)))
#define LDS_AS    __attribute__((address_space(3)))

__device__ __forceinline__ void gload_lds16(const void* g, void* l) {
    __builtin_amdgcn_global_load_lds((const GLOBAL_AS void*)g,
                                     (LDS_AS void*)l, 16, 0, 0);
}

// ---------------- amax reduction (per-tensor) ----------------
__global__ void amax_kernel(const float* __restrict__ p, size_t n4,
                            float* __restrict__ out) {
    const float4* p4 = (const float4*)p;
    float m = 0.f;
    for (size_t i = (size_t)blockIdx.x * blockDim.x + threadIdx.x; i < n4;
         i += (size_t)gridDim.x * blockDim.x) {
        float4 v = p4[i];
        m = fmaxf(m, fmaxf(fmaxf(fabsf(v.x), fabsf(v.y)),
                           fmaxf(fabsf(v.z), fabsf(v.w))));
    }
    #pragma unroll
    for (int off = 32; off > 0; off >>= 1)
        m = fmaxf(m, __shfl_down(m, off, 64));
    __shared__ float sm[4];
    int wid = threadIdx.x >> 6;
    if ((threadIdx.x & 63) == 0) sm[wid] = m;
    __syncthreads();
    if (threadIdx.x == 0) {
        m = fmaxf(fmaxf(sm[0], sm[1]), fmaxf(sm[2], sm[3]));
        atomicMax((unsigned int*)out, __float_as_uint(m));
    }
}

// ---------------- fp8 e4m3 quantization (16 elems/thread) ----------------
__global__ void quant_kernel(const float* __restrict__ p, size_t n16,
                             const float* __restrict__ amax_p,
                             uint32_t* __restrict__ q) {
    const float scale = 448.f / fmaxf(*amax_p, 1e-12f);
    size_t i = (size_t)blockIdx.x * blockDim.x + threadIdx.x;
    if (i >= n16) return;
    const float4* src = (const float4*)p + i * 4;
    uint32_t r[4];
    #pragma unroll
    for (int j = 0; j < 4; ++j) {
        float4 v = src[j];
        uint32_t u = __builtin_amdgcn_cvt_pk_fp8_f32(v.x * scale, v.y * scale, 0u, false);
        u = __builtin_amdgcn_cvt_pk_fp8_f32(v.z * scale, v.w * scale, u, true);
        r[j] = u;
    }
    uint4 out;
    out.x = r[0]; out.y = r[1]; out.z = r[2]; out.w = r[3];
    *(uint4*)(q + i * 4) = out;
}

// ---------------- fp8 GEMM: C[M][N] = A[M][K] * B[N][K]^T ----------------
#define BM 128
#define BN 128
#define BK 64

__global__ __launch_bounds__(256) void gemm_fp8_kernel(
    const uint8_t* __restrict__ Aq,   // [M][K] fp8
    const uint8_t* __restrict__ Bq,   // [N][K] fp8
    const float* __restrict__ scal,   // {amax_x, amax_w}
    const float* __restrict__ bias,   // [N] f32 holding fp16-exact values
    float* __restrict__ C,            // [M][N] f32 (fp16-rounded values)
    int M, int N, int K)
{
    __shared__ uint8_t As[BM * BK];   // 8 KB
    __shared__ uint8_t Bs[BN * BK];   // 8 KB

    const int tid  = threadIdx.x;
    const int wid  = tid >> 6;
    const int lane = tid & 63;
    const int wm = wid >> 1, wn = wid & 1;   // 2x2 waves, 64x64 each
    const int bn = blockIdx.x, bm = blockIdx.y;
    const int r16 = lane & 15, hi = lane >> 4;

    const uint8_t* Abase = Aq + (size_t)bm * BM * K;
    const uint8_t* Bbase = Bq + (size_t)bn * BN * K;

    // staging: chunk c = i*4+wid covers lds bytes [c*1024, c*1024+1024)
    // lane stages 16B at c*1024 + lane*16  -> row = off/64, col = off%64
    int srow[2], scol[2];
    #pragma unroll
    for (int i = 0; i < 2; ++i) {
        int off = (i * 4 + wid) * 1024 + lane * 16;
        srow[i] = off >> 6;
        scol[i] = off & 63;
    }

    f32x4 acc[4][4] = {};

    for (int k0 = 0; k0 < K; k0 += BK) {
        #pragma unroll
        for (int i = 0; i < 2; ++i) {
            gload_lds16(Abase + (size_t)srow[i] * K + k0 + scol[i],
                        As + (i * 4 + wid) * 1024);
            gload_lds16(Bbase + (size_t)srow[i] * K + k0 + scol[i],
                        Bs + (i * 4 + wid) * 1024);
        }
        __syncthreads();

        long a[4][2], b[4][2];
        #pragma unroll
        for (int mi = 0; mi < 4; ++mi) {
            #pragma unroll
            for (int ks = 0; ks < 2; ++ks) {
                a[mi][ks] = *(const long*)(As + (wm * 64 + mi * 16 + r16) * 64 + ks * 32 + hi * 8);
                b[mi][ks] = *(const long*)(Bs + (wn * 64 + mi * 16 + r16) * 64 + ks * 32 + hi * 8);
            }
        }
        #pragma unroll
        for (int mi = 0; mi < 4; ++mi)
            #pragma unroll
            for (int nj = 0; nj < 4; ++nj)
                #pragma unroll
                for (int ks = 0; ks < 2; ++ks)
                    acc[mi][nj] = __builtin_amdgcn_mfma_f32_16x16x32_fp8_fp8(
                        a[mi][ks], b[nj][ks], acc[mi][nj], 0, 0, 0);
        __syncthreads();
    }

    // epilogue: scale, fp16-round, fp16 bias add, widen to f32
    const float sx = 448.f / fmaxf(scal[0], 1e-12f);
    const float sw = 448.f / fmaxf(scal[1], 1e-12f);
    const float inv = (1.f / sx) * (1.f / sw);

    #pragma unroll
    for (int mi = 0; mi < 4; ++mi) {
        #pragma unroll
        for (int nj = 0; nj < 4; ++nj) {
            int col = bn * BN + wn * 64 + nj * 16 + r16;
            __half hb = __float2half(bias[col]);   // bias stored as f32 (fp16-exact)
            #pragma unroll
            for (int r = 0; r < 4; ++r) {
                int row = bm * BM + wm * 64 + mi * 16 + hi * 4 + r;
                float v = acc[mi][nj][r] * inv;
                __half h = __hadd(__float2half(v), hb);
                C[(size_t)row * N + col] = __half2float(h);
            }
        }
    }
}

extern "C" void kernel_launch(void* const* d_in, const int* in_sizes, int n_in,
                              void* d_out, int out_size, void* d_ws, size_t ws_size,
                              hipStream_t stream) {
    const float* x    = (const float*)d_in[0];
    const float* w    = (const float*)d_in[1];
    const float* bias = (const float*)d_in[2];   // fp16 in reference -> f32 on device
    float* out = (float*)d_out;

    const int N = in_sizes[2];              // 8192
    const int K = in_sizes[1] / N;          // 2048
    const int M = in_sizes[0] / K;          // 16384

    uint8_t* ws = (uint8_t*)d_ws;
    float* scal = (float*)ws;               // [0]=amax_x, [1]=amax_w
    uint8_t* Aq = ws + 256;
    uint8_t* Bq = Aq + (size_t)M * K;

    hipMemsetAsync(scal, 0, 8, stream);

    amax_kernel<<<2048, 256, 0, stream>>>(x, (size_t)M * K / 4, scal);
    amax_kernel<<<2048, 256, 0, stream>>>(w, (size_t)N * K / 4, scal + 1);

    size_t nx16 = (size_t)M * K / 16;
    size_t nw16 = (size_t)N * K / 16;
    quant_kernel<<<(int)((nx16 + 255) / 256), 256, 0, stream>>>(x, nx16, scal, (uint32_t*)Aq);
    quant_kernel<<<(int)((nw16 + 255) / 256), 256, 0, stream>>>(w, nw16, scal + 1, (uint32_t*)Bq);

    dim3 grid(N / BN, M / BM);
    gemm_fp8_kernel<<<grid, 256, 0, stream>>>(Aq, Bq, scal, bias, out, M, N, K);
}

// Round 3
// 468.511 us; speedup vs baseline: 2.3827x; 2.3827x over previous
//
#include <hip/hip_runtime.h>
#include <hip/hip_fp16.h>
#include <stdint.h>
#include <stddef.h>

typedef float f32x4 __attribute__((ext_vector_type(4)));
typedef int   i32x8 __attribute__((ext_vector_type(8)));

#define GLOBAL_AS __attribute__((address_space(1)))
#define LDS_AS    __attribute__((address_space(3)))

__device__ __forceinline__ void gload_lds16(const void* g, void* l) {
    __builtin_amdgcn_global_load_lds((const GLOBAL_AS void*)g,
                                     (LDS_AS void*)l, 16, 0, 0);
}

// ---------------- amax reduction (per-tensor) ----------------
__global__ void amax_kernel(const float* __restrict__ p, size_t n4,
                            float* __restrict__ out) {
    const float4* p4 = (const float4*)p;
    float m = 0.f;
    for (size_t i = (size_t)blockIdx.x * blockDim.x + threadIdx.x; i < n4;
         i += (size_t)gridDim.x * blockDim.x) {
        float4 v = p4[i];
        m = fmaxf(m, fmaxf(fmaxf(fabsf(v.x), fabsf(v.y)),
                           fmaxf(fabsf(v.z), fabsf(v.w))));
    }
    #pragma unroll
    for (int off = 32; off > 0; off >>= 1)
        m = fmaxf(m, __shfl_down(m, off, 64));
    __shared__ float sm[4];
    int wid = threadIdx.x >> 6;
    if ((threadIdx.x & 63) == 0) sm[wid] = m;
    __syncthreads();
    if (threadIdx.x == 0) {
        m = fmaxf(fmaxf(sm[0], sm[1]), fmaxf(sm[2], sm[3]));
        atomicMax((unsigned int*)out, __float_as_uint(m));
    }
}

// ---------------- fp8 e4m3 quantization (16 elems/thread) ----------------
__global__ void quant_kernel(const float* __restrict__ p, size_t n16,
                             const float* __restrict__ amax_p,
                             uint32_t* __restrict__ q) {
    const float scale = 448.f / fmaxf(*amax_p, 1e-12f);
    size_t i = (size_t)blockIdx.x * blockDim.x + threadIdx.x;
    if (i >= n16) return;
    const float4* src = (const float4*)p + i * 4;
    uint32_t r[4];
    #pragma unroll
    for (int j = 0; j < 4; ++j) {
        float4 v = src[j];
        uint32_t u = __builtin_amdgcn_cvt_pk_fp8_f32(v.x * scale, v.y * scale, 0u, false);
        u = __builtin_amdgcn_cvt_pk_fp8_f32(v.z * scale, v.w * scale, u, true);
        r[j] = u;
    }
    uint4 out;
    out.x = r[0]; out.y = r[1]; out.z = r[2]; out.w = r[3];
    *(uint4*)(q + i * 4) = out;
}

// ------- MX-fp8 GEMM (unit scales): C[M][N] = A[M][K] * B[N][K]^T -------
// mfma_scale_f32_16x16x128_f8f6f4, scales = E8M0 0x7F (1.0) -> exact fp8 GEMM
// LDS tiles [128 rows][128 B], 16B-chunk XOR swizzle u ^= (row&7):
//   - staging: linear LDS dest, pre-swizzled GLOBAL source (rule #21)
//   - read: lane (r16,hi) fetches its 32 k-bytes as 2x b128 at swizzled slots
#define BM 128
#define BN 128
#define BK 128

__global__ __launch_bounds__(256) void gemm_mxfp8_kernel(
    const uint8_t* __restrict__ Aq,   // [M][K] fp8
    const uint8_t* __restrict__ Bq,   // [N][K] fp8
    const float* __restrict__ scal,   // {amax_x, amax_w}
    const float* __restrict__ bias,   // [N] f32 holding fp16-exact values
    float* __restrict__ C,            // [M][N] f32 (fp16-rounded values)
    int M, int N, int K)
{
    __shared__ __align__(16) uint8_t As[BM * BK];   // 16 KB
    __shared__ __align__(16) uint8_t Bs[BN * BK];   // 16 KB

    const int tid  = threadIdx.x;
    const int wid  = tid >> 6;
    const int lane = tid & 63;
    const int wm = wid >> 1, wn = wid & 1;   // 2x2 waves, 64x64 each
    const int bn = blockIdx.x, bm = blockIdx.y;
    const int r16 = lane & 15, hi = lane >> 4;

    // ---- staging addresses (pre-swizzled global source) ----
    // round rho: LDS bytes [rho*4096 + wid*1024 + lane*16, +16)
    //   row  = rho*32 + wid*8 + (lane>>3)   (row&7 == lane>>3)
    //   slot = lane&7 ; content must be global chunk slot^(row&7)
    const int srow  = wid * 8 + (lane >> 3);
    const int schunk = ((lane & 7) ^ (lane >> 3)) << 4;
    const uint8_t* Abase = Aq + (size_t)(bm * BM + srow) * K + schunk;
    const uint8_t* Bbase = Bq + (size_t)(bn * BN + srow) * K + schunk;

    // ---- fragment-read swizzle: row&7 == r16&7 for all mi ----
    const int swz = r16 & 7;
    const int u0 = ((hi * 2)     ^ swz) << 4;
    const int u1 = ((hi * 2 + 1) ^ swz) << 4;

    f32x4 acc[4][4] = {};

    for (int k0 = 0; k0 < K; k0 += BK) {
        #pragma unroll
        for (int rho = 0; rho < 4; ++rho) {
            gload_lds16(Abase + (size_t)rho * 32 * K + k0,
                        As + rho * 4096 + wid * 1024);
            gload_lds16(Bbase + (size_t)rho * 32 * K + k0,
                        Bs + rho * 4096 + wid * 1024);
        }
        __syncthreads();

        i32x8 a[4], b[4];
        #pragma unroll
        for (int mi = 0; mi < 4; ++mi) {
            const uint8_t* pa = As + (wm * 64 + mi * 16 + r16) * BK;
            int4 qa0 = *(const int4*)(pa + u0);
            int4 qa1 = *(const int4*)(pa + u1);
            a[mi] = (i32x8){qa0.x, qa0.y, qa0.z, qa0.w,
                            qa1.x, qa1.y, qa1.z, qa1.w};
            const uint8_t* pb = Bs + (wn * 64 + mi * 16 + r16) * BK;
            int4 qb0 = *(const int4*)(pb + u0);
            int4 qb1 = *(const int4*)(pb + u1);
            b[mi] = (i32x8){qb0.x, qb0.y, qb0.z, qb0.w,
                            qb1.x, qb1.y, qb1.z, qb1.w};
        }

        #pragma unroll
        for (int mi = 0; mi < 4; ++mi)
            #pragma unroll
            for (int nj = 0; nj < 4; ++nj)
                acc[mi][nj] = __builtin_amdgcn_mfma_scale_f32_16x16x128_f8f6f4(
                    a[mi], b[nj], acc[mi][nj],
                    0 /*cbsz: A=fp8*/, 0 /*blgp: B=fp8*/,
                    0, 0x7F7F7F7F,   // scale_a opsel, scale_a (E8M0 1.0)
                    0, 0x7F7F7F7F);  // scale_b opsel, scale_b
        __syncthreads();
    }

    // epilogue: scale, fp16-round, fp16 bias add, widen to f32
    const float sx = 448.f / fmaxf(scal[0], 1e-12f);
    const float sw = 448.f / fmaxf(scal[1], 1e-12f);
    const float inv = (1.f / sx) * (1.f / sw);

    #pragma unroll
    for (int mi = 0; mi < 4; ++mi) {
        #pragma unroll
        for (int nj = 0; nj < 4; ++nj) {
            int col = bn * BN + wn * 64 + nj * 16 + r16;
            __half hb = __float2half(bias[col]);
            #pragma unroll
            for (int r = 0; r < 4; ++r) {
                int row = bm * BM + wm * 64 + mi * 16 + hi * 4 + r;
                float v = acc[mi][nj][r] * inv;
                __half h = __hadd(__float2half(v), hb);
                C[(size_t)row * N + col] = __half2float(h);
            }
        }
    }
}

extern "C" void kernel_launch(void* const* d_in, const int* in_sizes, int n_in,
                              void* d_out, int out_size, void* d_ws, size_t ws_size,
                              hipStream_t stream) {
    const float* x    = (const float*)d_in[0];
    const float* w    = (const float*)d_in[1];
    const float* bias = (const float*)d_in[2];   // fp16 in reference -> f32 on device
    float* out = (float*)d_out;

    const int N = in_sizes[2];              // 8192
    const int K = in_sizes[1] / N;          // 2048
    const int M = in_sizes[0] / K;          // 16384

    uint8_t* ws = (uint8_t*)d_ws;
    float* scal = (float*)ws;               // [0]=amax_x, [1]=amax_w
    uint8_t* Aq = ws + 256;
    uint8_t* Bq = Aq + (size_t)M * K;

    hipMemsetAsync(scal, 0, 8, stream);

    amax_kernel<<<2048, 256, 0, stream>>>(x, (size_t)M * K / 4, scal);
    amax_kernel<<<2048, 256, 0, stream>>>(w, (size_t)N * K / 4, scal + 1);

    size_t nx16 = (size_t)M * K / 16;
    size_t nw16 = (size_t)N * K / 16;
    quant_kernel<<<(int)((nx16 + 255) / 256), 256, 0, stream>>>(x, nx16, scal, (uint32_t*)Aq);
    quant_kernel<<<(int)((nw16 + 255) / 256), 256, 0, stream>>>(w, nw16, scal + 1, (uint32_t*)Bq);

    dim3 grid(N / BN, M / BM);
    gemm_mxfp8_kernel<<<grid, 256, 0, stream>>>(Aq, Bq, scal, bias, out, M, N, K);
}